// Round 4
// baseline (648.104 us; speedup 1.0000x reference)
//
#include <hip/hip_runtime.h>

#define MM 2048   // memory slots
#define BB 64     // batch
#define TT 4      // tokens per slot
#define DD 128    // embed dim
#define VV 50000  // vocab
#define VPAD 50176  // VV rounded up to multiple of 256

// ---- zero u ----
__global__ void k_zero(float* __restrict__ u) {
    u[blockIdx.x * 256 + threadIdx.x] = 0.f;
}

// ---- zero W (float4 per thread) ----
__global__ void k_zero_w(float4* __restrict__ w) {
    w[blockIdx.x * 256 + threadIdx.x] = make_float4(0.f, 0.f, 0.f, 0.f);
}

// ---- GEMM1: P[v][b] = dot(C[h][v][:], u[b][:]) ----
// lane = b. Each thread register-caches u[:, b] (128 VGPRs) via a padded LDS
// transpose. Per v: 32 wave-uniform float4 loads of the C row (no LDS in the
// hot loop) + 128 FMAs in 4 accumulator chains. Wave handles 16 v's.
__global__ __launch_bounds__(256, 3) void k_gemm_p(const float* __restrict__ Ch,
                                                   const float* __restrict__ u,
                                                   float* __restrict__ P) {
    __shared__ float uT[DD * 65];  // [d][b], stride 65 -> conflict-free
    const int t = threadIdx.x;

    // stage u ([b][d] global) transposed into LDS [d][b]
#pragma unroll
    for (int k = 0; k < 32; ++k) {
        const int f = k * 256 + t;  // f = b*128 + d
        uT[(f & 127) * 65 + (f >> 7)] = u[f];
    }
    __syncthreads();

    const int lane = t & 63;
    float ureg[128];
#pragma unroll
    for (int d = 0; d < 128; ++d) ureg[d] = uT[d * 65 + lane];

    const int wv = __builtin_amdgcn_readfirstlane(t >> 6);
    const int v0 = (blockIdx.x * 4 + wv) * 16;

    for (int vi = 0; vi < 16; ++vi) {
        const int v = v0 + vi;
        if (v >= VV) continue;  // wave-uniform; P pad rows never read
        const float* __restrict__ Crow = Ch + (size_t)v * DD;
        float a0 = 0.f, a1 = 0.f, a2 = 0.f, a3 = 0.f;
#pragma unroll
        for (int d4 = 0; d4 < 32; ++d4) {
            const float4 c4 = *(const float4*)(Crow + d4 * 4);
            a0 += c4.x * ureg[d4 * 4 + 0];
            a1 += c4.y * ureg[d4 * 4 + 1];
            a2 += c4.z * ureg[d4 * 4 + 2];
            a3 += c4.w * ureg[d4 * 4 + 3];
        }
        P[(size_t)v * 64 + lane] = (a0 + a1) + (a2 + a3);
    }
}

// ---- gather scores: s[m*64+b] = sum_t (tok!=0) P[tok*64+b] ----
__global__ __launch_bounds__(256) void k_gather(const int* __restrict__ st,
                                                const float* __restrict__ P,
                                                float* __restrict__ s) {
    const int g = blockIdx.x * 256 + threadIdx.x;  // g = m*64+b
    const int b = g & 63;
    const int4 tk = *(const int4*)(st + (size_t)g * 4);
    float acc = 0.f;
    if (tk.x) acc += P[(size_t)tk.x * 64 + b];
    if (tk.y) acc += P[(size_t)tk.y * 64 + b];
    if (tk.z) acc += P[(size_t)tk.z * 64 + b];
    if (tk.w) acc += P[(size_t)tk.w * 64 + b];
    s[g] = acc;
}

// ---- softmax over m for each b; s layout [m][b] ----
__global__ __launch_bounds__(256) void k_softmax(float* __restrict__ s) {
    const int b = blockIdx.x;
    const int tid = threadIdx.x;  // 256
    __shared__ float redmax[4];
    __shared__ float redsum[4];

    float v[8];
    float mx = -1e30f;
#pragma unroll
    for (int i = 0; i < 8; ++i) {
        v[i] = s[(size_t)(tid + 256 * i) * 64 + b];
        mx = fmaxf(mx, v[i]);
    }
#pragma unroll
    for (int off = 32; off; off >>= 1) mx = fmaxf(mx, __shfl_xor(mx, off, 64));
    if ((tid & 63) == 0) redmax[tid >> 6] = mx;
    __syncthreads();
    const float gmax = fmaxf(fmaxf(redmax[0], redmax[1]),
                             fmaxf(redmax[2], redmax[3]));

    float sum = 0.f;
#pragma unroll
    for (int i = 0; i < 8; ++i) {
        v[i] = __expf(v[i] - gmax);
        sum += v[i];
    }
#pragma unroll
    for (int off = 32; off; off >>= 1) sum += __shfl_xor(sum, off, 64);
    if ((tid & 63) == 0) redsum[tid >> 6] = sum;
    __syncthreads();
    const float inv = 1.f / (redsum[0] + redsum[1] + redsum[2] + redsum[3]);
#pragma unroll
    for (int i = 0; i < 8; ++i)
        s[(size_t)(tid + 256 * i) * 64 + b] = v[i] * inv;
}

// ---- scatter: W[tok*64+b] += prob[m,b] (coalesced 256B atomics per token) ----
__global__ __launch_bounds__(256) void k_scatter(const int* __restrict__ st,
                                                 const float* __restrict__ s,
                                                 float* __restrict__ W) {
    const int g = blockIdx.x * 256 + threadIdx.x;  // g = m*64+b
    const int b = g & 63;
    const float p = s[g];
    const int4 tk = *(const int4*)(st + (size_t)g * 4);
    if (tk.x) atomicAdd(W + (size_t)tk.x * 64 + b, p);
    if (tk.y) atomicAdd(W + (size_t)tk.y * 64 + b, p);
    if (tk.z) atomicAdd(W + (size_t)tk.z * 64 + b, p);
    if (tk.w) atomicAdd(W + (size_t)tk.w * 64 + b, p);
}

// ---- GEMM2: u[b][d] += sum_v W[v][b] * C2[v][d] ----
// lane = d (within half), acc[64] = all b in registers. Per v: one coalesced
// C2 load + 16 wave-uniform float4 loads of W row + 64 FMAs. No LDS.
// Block: wave-pair p covers 64 v's, d-halves split across waves.
__global__ __launch_bounds__(256, 4) void k_gemm_o(const float* __restrict__ C2,
                                                   const float* __restrict__ W,
                                                   float* __restrict__ u) {
    const int t = threadIdx.x;
    const int lane = t & 63;
    const int dhalf = (t >> 6) & 1;
    const int d = lane + dhalf * 64;
    const int p = __builtin_amdgcn_readfirstlane(t >> 7);
    const int vbase = blockIdx.x * 128 + p * 64;

    float acc[64];
#pragma unroll
    for (int j = 0; j < 64; ++j) acc[j] = 0.f;

#pragma unroll 2
    for (int i = 0; i < 64; ++i) {
        const int v = vbase + i;
        const float c = (v < VV) ? C2[(size_t)v * DD + d] : 0.f;
        const float* __restrict__ Wrow = W + (size_t)v * 64;
#pragma unroll
        for (int j4 = 0; j4 < 16; ++j4) {
            const float4 w4 = *(const float4*)(Wrow + j4 * 4);
            acc[j4 * 4 + 0] += w4.x * c;
            acc[j4 * 4 + 1] += w4.y * c;
            acc[j4 * 4 + 2] += w4.z * c;
            acc[j4 * 4 + 3] += w4.w * c;
        }
    }
#pragma unroll
    for (int j = 0; j < 64; ++j)
        atomicAdd(u + (size_t)j * DD + d, acc[j]);
}

// ---- copy u -> out ----
__global__ void k_copy(const float* __restrict__ u, float* __restrict__ out) {
    const int i = blockIdx.x * 256 + threadIdx.x;
    out[i] = u[i];
}

extern "C" void kernel_launch(void* const* d_in, const int* in_sizes, int n_in,
                              void* d_out, int out_size, void* d_ws, size_t ws_size,
                              hipStream_t stream) {
    const int* st = (const int*)d_in[0];
    const float* C = (const float*)d_in[1];

    float* u  = (float*)d_ws;            // 64*128 = 32 KB, layout [b][d]
    float* s  = u + BB * DD;             // 2048*64 = 512 KB, layout [m][b]
    float* PW = s + MM * BB;             // VPAD*64 fp32 = 12.85 MB (P/W share)

    k_zero<<<(BB * DD) / 256, 256, 0, stream>>>(u);

    for (int hop = 0; hop < 3; ++hop) {
        const float* Ch  = C + (size_t)hop * VV * DD;
        const float* Ch1 = C + (size_t)(hop + 1) * VV * DD;

        k_gemm_p<<<VPAD / 64, 256, 0, stream>>>(Ch, u, PW);          // 784 blocks
        k_gather<<<(MM * BB) / 256, 256, 0, stream>>>(st, PW, s);    // 512
        k_softmax<<<BB, 256, 0, stream>>>(s);                        // 64
        k_zero_w<<<(VPAD * BB / 4) / 256, 256, 0, stream>>>((float4*)PW);  // 3136
        k_scatter<<<(MM * BB) / 256, 256, 0, stream>>>(st, s, PW);   // 512
        k_gemm_o<<<VPAD / 128, 256, 0, stream>>>(Ch1, PW, u);        // 392
    }

    k_copy<<<(BB * DD) / 256, 256, 0, stream>>>(u, (float*)d_out);
}

// Round 5
// 588.578 us; speedup vs baseline: 1.1011x; 1.1011x over previous
//
#include <hip/hip_runtime.h>

#define MM 2048   // memory slots
#define BB 64     // batch
#define TT 4      // tokens per slot
#define DD 128    // embed dim
#define VV 50000  // vocab
#define VPAD 50176  // VV rounded up to multiple of 256

// ---- zero u ----
__global__ void k_zero(float* __restrict__ u) {
    u[blockIdx.x * 256 + threadIdx.x] = 0.f;
}

// ---- zero W (float4 per thread) ----
__global__ void k_zero_w(float4* __restrict__ w) {
    w[blockIdx.x * 256 + threadIdx.x] = make_float4(0.f, 0.f, 0.f, 0.f);
}

// ---- GEMM1: P[v][b] = dot(C[h][v][:], u[b][:]) ----
// Block = 4 waves; wave w owns K-quarter [w*32, w*32+32), lane = b.
// Thread state: ureg[32] (its u slice) + acc[16] (16 v-rows) — fully
// unrolled so everything stays in VGPRs. C loads are wave-uniform
// (broadcast/scalar). Partials across the 4 waves combined via LDS.
__global__ __launch_bounds__(256, 3) void k_gemm_p(const float* __restrict__ Ch,
                                                   const float* __restrict__ u,
                                                   float* __restrict__ P) {
    __shared__ float uT[DD * 65];      // [d][b], stride 65 (33.3 KB)
    __shared__ float pbuf[4 * 16 * 64]; // [w][vi][b] partials (16 KB)
    const int t = threadIdx.x;
    const int lane = t & 63;  // = b
    const int w = __builtin_amdgcn_readfirstlane(t >> 6);

    // stage u ([b][d] global, coalesced float4) transposed into uT [d][b]
#pragma unroll
    for (int k = 0; k < 8; ++k) {
        const int f = (k * 256 + t) * 4;  // f = b*128 + d
        const int b = f >> 7, d = f & 127;
        const float4 val = *(const float4*)(u + f);
        uT[(d + 0) * 65 + b] = val.x;
        uT[(d + 1) * 65 + b] = val.y;
        uT[(d + 2) * 65 + b] = val.z;
        uT[(d + 3) * 65 + b] = val.w;
    }
    __syncthreads();

    // thread caches its K-quarter of u[b][:]  (2-way bank access: free)
    float ureg[32];
#pragma unroll
    for (int j = 0; j < 32; ++j) ureg[j] = uT[(w * 32 + j) * 65 + lane];

    const int v0 = blockIdx.x * 16;
    float acc[16];
#pragma unroll
    for (int vi = 0; vi < 16; ++vi) acc[vi] = 0.f;

#pragma unroll
    for (int vi = 0; vi < 16; ++vi) {
        const int v = v0 + vi;
        if (v < VV) {  // wave-uniform
            const float* __restrict__ Crow = Ch + (size_t)v * DD + w * 32;
#pragma unroll
            for (int d4 = 0; d4 < 8; ++d4) {
                const float4 c4 = *(const float4*)(Crow + d4 * 4);
                acc[vi] += c4.x * ureg[d4 * 4 + 0];
                acc[vi] += c4.y * ureg[d4 * 4 + 1];
                acc[vi] += c4.z * ureg[d4 * 4 + 2];
                acc[vi] += c4.w * ureg[d4 * 4 + 3];
            }
        }
    }

    // combine 4 wave-partials via LDS, coalesced store to P
#pragma unroll
    for (int vi = 0; vi < 16; ++vi)
        pbuf[w * 1024 + vi * 64 + lane] = acc[vi];
    __syncthreads();
#pragma unroll
    for (int k = 0; k < 4; ++k) {
        const int o = k * 256 + t;  // o = vi*64 + b
        const float sum = pbuf[o] + pbuf[1024 + o] + pbuf[2048 + o] + pbuf[3072 + o];
        const int v = v0 + (o >> 6);
        if (v < VV) P[(size_t)v * 64 + (o & 63)] = sum;
    }
}

// ---- gather scores: s[m*64+b] = sum_t (tok!=0) P[tok*64+b] ----
__global__ __launch_bounds__(256) void k_gather(const int* __restrict__ st,
                                                const float* __restrict__ P,
                                                float* __restrict__ s) {
    const int g = blockIdx.x * 256 + threadIdx.x;  // g = m*64+b
    const int b = g & 63;
    const int4 tk = *(const int4*)(st + (size_t)g * 4);
    float acc = 0.f;
    if (tk.x) acc += P[(size_t)tk.x * 64 + b];
    if (tk.y) acc += P[(size_t)tk.y * 64 + b];
    if (tk.z) acc += P[(size_t)tk.z * 64 + b];
    if (tk.w) acc += P[(size_t)tk.w * 64 + b];
    s[g] = acc;
}

// ---- softmax over m for each b; s layout [m][b] ----
__global__ __launch_bounds__(256) void k_softmax(float* __restrict__ s) {
    const int b = blockIdx.x;
    const int tid = threadIdx.x;  // 256
    __shared__ float redmax[4];
    __shared__ float redsum[4];

    float v[8];
    float mx = -1e30f;
#pragma unroll
    for (int i = 0; i < 8; ++i) {
        v[i] = s[(size_t)(tid + 256 * i) * 64 + b];
        mx = fmaxf(mx, v[i]);
    }
#pragma unroll
    for (int off = 32; off; off >>= 1) mx = fmaxf(mx, __shfl_xor(mx, off, 64));
    if ((tid & 63) == 0) redmax[tid >> 6] = mx;
    __syncthreads();
    const float gmax = fmaxf(fmaxf(redmax[0], redmax[1]),
                             fmaxf(redmax[2], redmax[3]));

    float sum = 0.f;
#pragma unroll
    for (int i = 0; i < 8; ++i) {
        v[i] = __expf(v[i] - gmax);
        sum += v[i];
    }
#pragma unroll
    for (int off = 32; off; off >>= 1) sum += __shfl_xor(sum, off, 64);
    if ((tid & 63) == 0) redsum[tid >> 6] = sum;
    __syncthreads();
    const float inv = 1.f / (redsum[0] + redsum[1] + redsum[2] + redsum[3]);
#pragma unroll
    for (int i = 0; i < 8; ++i)
        s[(size_t)(tid + 256 * i) * 64 + b] = v[i] * inv;
}

// ---- scatter: W[tok*64+b] += prob[m,b] ----
__global__ __launch_bounds__(256) void k_scatter(const int* __restrict__ st,
                                                 const float* __restrict__ s,
                                                 float* __restrict__ W) {
    const int g = blockIdx.x * 256 + threadIdx.x;  // g = m*64+b
    const int b = g & 63;
    const float p = s[g];
    const int4 tk = *(const int4*)(st + (size_t)g * 4);
    if (tk.x) atomicAdd(W + (size_t)tk.x * 64 + b, p);
    if (tk.y) atomicAdd(W + (size_t)tk.y * 64 + b, p);
    if (tk.z) atomicAdd(W + (size_t)tk.z * 64 + b, p);
    if (tk.w) atomicAdd(W + (size_t)tk.w * 64 + b, p);
}

// ---- GEMM2: u[b][d] += sum_v W[v][b] * C2[v][d] ----
// d = t&127 (wave pair), b-half = t>>7 -> acc[32]. C2 coalesced, W row
// wave-uniform float4 broadcasts. 128 v per block, atomicAdd epilogue.
__global__ __launch_bounds__(256, 4) void k_gemm_o(const float* __restrict__ C2,
                                                   const float* __restrict__ W,
                                                   float* __restrict__ u) {
    const int t = threadIdx.x;
    const int d = t & 127;
    const int b0 = __builtin_amdgcn_readfirstlane(t >> 7) * 32;
    const int vbase = blockIdx.x * 128;

    float acc[32];
#pragma unroll
    for (int j = 0; j < 32; ++j) acc[j] = 0.f;

#pragma unroll 2
    for (int i = 0; i < 128; ++i) {
        const int v = vbase + i;
        const float c = (v < VV) ? C2[(size_t)v * DD + d] : 0.f;
        const float* __restrict__ Wrow = W + (size_t)v * 64 + b0;
#pragma unroll
        for (int j4 = 0; j4 < 8; ++j4) {
            const float4 w4 = *(const float4*)(Wrow + j4 * 4);
            acc[j4 * 4 + 0] += w4.x * c;
            acc[j4 * 4 + 1] += w4.y * c;
            acc[j4 * 4 + 2] += w4.z * c;
            acc[j4 * 4 + 3] += w4.w * c;
        }
    }
#pragma unroll
    for (int j = 0; j < 32; ++j)
        atomicAdd(u + (size_t)(b0 + j) * DD + d, acc[j]);
}

// ---- copy u -> out ----
__global__ void k_copy(const float* __restrict__ u, float* __restrict__ out) {
    const int i = blockIdx.x * 256 + threadIdx.x;
    out[i] = u[i];
}

extern "C" void kernel_launch(void* const* d_in, const int* in_sizes, int n_in,
                              void* d_out, int out_size, void* d_ws, size_t ws_size,
                              hipStream_t stream) {
    const int* st = (const int*)d_in[0];
    const float* C = (const float*)d_in[1];

    float* u  = (float*)d_ws;            // 64*128 = 32 KB, layout [b][d]
    float* s  = u + BB * DD;             // 2048*64 = 512 KB, layout [m][b]
    float* PW = s + MM * BB;             // VPAD*64 fp32 = 12.85 MB (P/W share)

    k_zero<<<(BB * DD) / 256, 256, 0, stream>>>(u);

    for (int hop = 0; hop < 3; ++hop) {
        const float* Ch  = C + (size_t)hop * VV * DD;
        const float* Ch1 = C + (size_t)(hop + 1) * VV * DD;

        k_gemm_p<<<VPAD / 16, 256, 0, stream>>>(Ch, u, PW);          // 3136 blocks
        k_gather<<<(MM * BB) / 256, 256, 0, stream>>>(st, PW, s);    // 512
        k_softmax<<<BB, 256, 0, stream>>>(s);                        // 64
        k_zero_w<<<(VPAD * BB / 4) / 256, 256, 0, stream>>>((float4*)PW);  // 3136
        k_scatter<<<(MM * BB) / 256, 256, 0, stream>>>(st, s, PW);   // 512
        k_gemm_o<<<VPAD / 128, 256, 0, stream>>>(Ch1, PW, u);        // 392
    }

    k_copy<<<(BB * DD) / 256, 256, 0, stream>>>(u, (float*)d_out);
}